// Round 20
// baseline (1090.884 us; speedup 1.0000x reference)
//
#include <hip/hip_runtime.h>
#include <cmath>

#define BATCH 32
#define SEQ   2048
#define EMB   512
#define NOUT  256
#define PS    16
#define KW    16
#define JTOT  8192  // K*E flat contraction length, j = k*512 + i (i fastest)
#define KCL   288   // Eigen threaded gebp kc (linear dot: 512 = 288 + 224)
#define KS    32    // j-tile; 288 = 9*KS, tail 128 = 4*KS -> panel folds align

// sA swizzled word index (64-word rows): row kk + XOR word bits 2-4 by kk&7.
// Bijective per row, preserves 16B quads (only bits>=2 touched).
#define SWA(kk_, mw_) (((kk_) << 6) + ((mw_) ^ (((kk_) & 7) << 2)))

// async global->LDS, 16B per lane, wave-uniform LDS base + lane*16 dest
#define GLDS16(g_, l_) __builtin_amdgcn_global_load_lds(                      \
    (__attribute__((address_space(1))) const void*)(g_),                      \
    (__attribute__((address_space(3))) void*)(l_), 16, 0, 0)

// XLA EmitFastTanh / Eigen ptanh_float: rational approx, f32, FMA Horner.
__device__ __forceinline__ float xla_tanhf(float x) {
#pragma clang fp contract(off)
    float ax = fabsf(x);
    float xc = x;
    if (xc < -7.90531110763549805f) xc = -7.90531110763549805f;
    if (xc >  7.90531110763549805f) xc =  7.90531110763549805f;
    float x2 = xc * xc;
    float p = __builtin_fmaf(x2, -2.76076847742355e-16f, 2.00018790482477e-13f);
    p = __builtin_fmaf(x2, p, -8.60467152213735e-11f);
    p = __builtin_fmaf(x2, p,  5.12229709037114e-08f);
    p = __builtin_fmaf(x2, p,  1.48572235717979e-05f);
    p = __builtin_fmaf(x2, p,  6.37261928875436e-04f);
    p = __builtin_fmaf(x2, p,  4.89352455891786e-03f);
    float num = xc * p;
    float q = __builtin_fmaf(x2, 1.19825839466702e-06f, 1.18534705686654e-04f);
    q = __builtin_fmaf(x2, q, 2.26843463243900e-03f);
    q = __builtin_fmaf(x2, q, 4.89352518554385e-03f);
    float r = num / q;
    return (ax < 0.0004f) ? x : r;
}

// K1: wT[j][o] = conv_w[o][i][k],  j = k*512 + i  (XLA/Eigen im2col order)
__global__ __launch_bounds__(256) void k_transpose_w(const float* __restrict__ w,
                                                     float* __restrict__ wT) {
    int t = blockIdx.x * 256 + threadIdx.x;   // t = j*512 + o
    int o = t & 511;
    int i = (t >> 9) & 511;
    int k = t >> 18;
    wT[t] = w[(size_t)o * 8192 + i * 16 + k];
}

// K2: conv1d as LDS-tiled f32 GEMM, bit-exact Eigen gebp accumulation.
// 4-wave/SIMD probe: 64m x 64o tile, 4x4 micro, 256 thr, grid (128,8) =
// 1024 blocks = 4 blocks/CU = 16 waves/CU = 4 waves/SIMD. LDS 32 KB/block.
//  - sA XOR-swizzled (zero write conflicts, 2-way reads = free)
//  - per kk per thread: 1 A b128 (16-group broadcast) + 1 B b128 (16-lane
//    broadcast) + 16 FMA -> per-CU LDS issue ~= VALU issue, TLP hides
//  - T14 order: LOAD_A (top) ... compute ... WRITE_A ... single barrier
//  - sB: global_load_lds DMA, lane-linear, zero regs, zero conflicts
// Per output: panels of kc=288 over j, sequential fmaf chain (pk), panels
// left-folded into ys at js%9==8 and js==255 -> identical bits to r9-r19.
__global__ __launch_bounds__(256, 4) void k_conv(const float* __restrict__ x,
                                                 const float* __restrict__ wT,
                                                 const float* __restrict__ cb,
                                                 float* __restrict__ y) {
#pragma clang fp contract(off)
    __shared__ __align__(16) float sA[2][KS * 64];    // 16 KB, swizzled [kk][m]
    __shared__ __align__(16) float sB[2][KS][64];     // 16 KB, linear (GLDS dest)

    int bn0 = blockIdx.x << 6;     // 0..127 -> 64-bn strip
    int b   = bn0 >> 8;
    int n0  = bn0 & 255;
    int o0  = blockIdx.y << 6;     // 0..7 -> 64-o strip

    int tid  = threadIdx.x;
    int tm   = tid & 15;           // 4 m-rows each (m = tm*4+mi)
    int tn   = tid >> 4;           // 4 o-cols each (o = tn*4+ni), 0..15
    int lane = tid & 63;
    int wv   = tid >> 6;           // wave id 0..3

    // A-staging role: thread = (kks 0..31, mg 0..7): col i0+kks, m-octet mg
    int kks = tid & 31;
    int mg  = tid >> 5;

    float ys[4][4], pk[4][4];
#pragma unroll
    for (int mi = 0; mi < 4; ++mi)
#pragma unroll
        for (int ni = 0; ni < 4; ++ni) { ys[mi][ni] = 0.0f; pk[mi][ni] = 0.0f; }

    const float* xb = x + (size_t)b * SEQ * EMB;

    float rs[8];   // A-stage regs (8 VGPR), only cross-compute liveness

    // A: 8 KB/js; thread loads 8 m-rows of its column (128B-coalesced/instr)
#define LOAD_A(js_)                                                            \
    {                                                                          \
        int k_ = (js_) >> 4;                                                   \
        const float* xcol = xb + ((((js_) & 15) << 5) + kks);                  \
        _Pragma("unroll")                                                      \
        for (int q = 0; q < 8; ++q) {                                          \
            int m = (mg << 3) + q;                                             \
            int s = ((n0 + m) << 3) - 4 + k_;                                  \
            rs[q] = (s >= 0 && s < SEQ) ? xcol[(size_t)s << 9] : 0.0f;         \
        }                                                                      \
    }

    // 2 b128 writes, XOR-swizzled: conflict-free
#define WRITE_A(bf_)                                                           \
    {                                                                          \
        _Pragma("unroll")                                                      \
        for (int wq = 0; wq < 2; ++wq) {                                       \
            float4 v = make_float4(rs[wq * 4], rs[wq * 4 + 1],                 \
                                   rs[wq * 4 + 2], rs[wq * 4 + 3]);            \
            *(float4*)&sA[bf_][SWA(kks, (mg << 3) + (wq << 2))] = v;           \
        }                                                                      \
    }

    // B: 8 KB/js; 2 DMA insts per wave, 4 kk-rows (256 B each) per inst
#define STAGE_B(js_, bf_)                                                      \
    {                                                                          \
        _Pragma("unroll")                                                      \
        for (int t2 = 0; t2 < 2; ++t2) {                                       \
            int kkb = (wv << 3) + (t2 << 2);                                   \
            const float* gsrc = wT + (((size_t)((js_) << 5) + kkb + (lane >> 4)) << 9) \
                                   + o0 + ((lane & 15) << 2);                  \
            GLDS16(gsrc, &sB[bf_][kkb][0]);                                    \
        }                                                                      \
    }

    // prologue: stage js=0 into buffer 0
    LOAD_A(0);
    WRITE_A(0);
    STAGE_B(0, 0);
    __syncthreads();

    for (int js = 0; js < 256; ++js) {
        int cur = js & 1;
        if (js < 255) {
            LOAD_A(js + 1);                // A loads first (oldest in vm queue)
            STAGE_B(js + 1, cur ^ 1);      // B DMAs younger -> WRITE_A won't drain them
        }

        // micro-kernel: pk chains ascend in kk (exact Eigen panel order)
#pragma unroll
        for (int kk = 0; kk < KS; ++kk) {
            float4 a = *(const float4*)&sA[cur][SWA(kk, tm << 2)];
            float4 bq = *(const float4*)&sB[cur][kk][tn << 2];
            float av[4] = {a.x, a.y, a.z, a.w};
            float bv[4] = {bq.x, bq.y, bq.z, bq.w};
#pragma unroll
            for (int mi = 0; mi < 4; ++mi)
#pragma unroll
                for (int ni = 0; ni < 4; ++ni)
                    pk[mi][ni] = __builtin_fmaf(av[mi], bv[ni], pk[mi][ni]);
        }
        // panel left-fold (ys += pk) at kc=288 boundaries and the 128 tail
        if ((js % 9) == 8 || js == 255) {
#pragma unroll
            for (int mi = 0; mi < 4; ++mi)
#pragma unroll
                for (int ni = 0; ni < 4; ++ni) {
                    ys[mi][ni] = ys[mi][ni] + pk[mi][ni];
                    pk[mi][ni] = 0.0f;
                }
        }
        // write A for js+1 (waits only the A loads; B DMAs stay in flight)
        if (js < 255) WRITE_A(cur ^ 1);
        __syncthreads();   // drains vmcnt(0) (B landed during compute), barrier
    }

    // epilogue: bias add (exact r9 order) + store
    const float* cbp = cb + o0 + (tn << 2);
#pragma unroll
    for (int mi = 0; mi < 4; ++mi) {
        int n = n0 + (tm << 2) + mi;
        float* dst = y + (((size_t)(b << 8) + n) << 9) + o0 + (tn << 2);
#pragma unroll
        for (int ni = 0; ni < 4; ++ni)
            dst[ni] = ys[mi][ni] + cbp[ni];
    }
#undef LOAD_A
#undef WRITE_A
#undef STAGE_B
}

// K3: per (b,n): off = relu(y) @ lin_w.T + lin_b with Eigen kc=288 panel split
// (512 = 288 + 224), then decode op-for-op in f32 (contract off), XLA tanh,
// jax-f32 linspace t (t = p * f32(1/15)).
__global__ __launch_bounds__(256) void k_decode(const float* __restrict__ y,
                                               const float* __restrict__ lw,
                                               const float* __restrict__ lb,
                                               const float* __restrict__ wb,
                                               int* __restrict__ idx) {
#pragma clang fp contract(off)
    int bn = blockIdx.x * 256 + threadIdx.x;   // 0..8191
    if (bn >= BATCH * NOUT) return;
    const float* yy = y + ((size_t)bn << 9);

    float s0, s1;
    {
        float p0 = 0.0f, p1 = 0.0f;
        for (int e = 0; e < KCL; ++e) {
            float v = yy[e];
            float r = v > 0.0f ? v : 0.0f;
            p0 = __builtin_fmaf(r, lw[e],       p0);
            p1 = __builtin_fmaf(r, lw[EMB + e], p1);
        }
        s0 = p0; s1 = p1;                  // panel 0 stores (beta=0)
    }
    {
        float p0 = 0.0f, p1 = 0.0f;
        for (int e = KCL; e < EMB; ++e) {
            float v = yy[e];
            float r = v > 0.0f ? v : 0.0f;
            p0 = __builtin_fmaf(r, lw[e],       p0);
            p1 = __builtin_fmaf(r, lw[EMB + e], p1);
        }
        s0 = s0 + p0; s1 = s1 + p1;        // panel 1 accumulates
    }
    float off0 = s0 + lb[0];
    float off1 = s1 + lb[1];

    int n = bn & (NOUT - 1);
    float anchor = (0.5f + (float)n) / 256.0f;        // exact in f32
    float dx  = xla_tanhf(off0) * 0.00390625f;        // * poi (2^-8, exact)
    float a1  = off1 + wb[0];
    float tww = xla_tanhf(a1);
    float rwv = tww > 0.0f ? tww : 0.0f;
    float dwv = rwv * 0.00390625f;
    float adx = anchor + dx;                          // left-assoc like jnp
    float x0 = adx - dwv; x0 = x0 < 0.0f ? 0.0f : (x0 > 1.0f ? 1.0f : x0);
    float x1 = adx + dwv; x1 = x1 < 0.0f ? 0.0f : (x1 > 1.0f ? 1.0f : x1);

    const float delta = 1.0f / 15.0f;                 // f32 0.06666667
#pragma unroll
    for (int p = 0; p < PS; ++p) {
        float t  = (float)p * delta;                  // jax linspace: iota*delta, f32
        float om = 1.0f - t;
        float gs = x0 * om + x1 * t;                  // mul,mul,add — contract off
        float gxn = 2.0f * gs - 1.0f;
        float gp1 = gxn + 1.0f;
        float ixx = (gp1 * 2048.0f - 1.0f) * 0.5f;
        float rr = rintf(ixx);                        // round half-even
        int id = (int)rr;
        id = id < 0 ? 0 : (id > SEQ - 1 ? SEQ - 1 : id);
        idx[bn * PS + p] = id;
    }
}

// K4: out[g][:] = x[b][idx[g]][:] (exact f32 row copy, 2048 B/row).
// Coarsened: 8 rows per block, 256 thr.
__global__ __launch_bounds__(256) void k_gather(const float* __restrict__ x,
                                                const int* __restrict__ idx,
                                                float* __restrict__ out) {
    int g0 = blockIdx.x << 3;           // first of 8 rows, 16384 blocks
    int r  = threadIdx.x >> 5;          // row 0..7
    int l  = threadIdx.x & 31;          // lane-in-row 0..31
    int g  = g0 + r;
    int b  = g >> 12;
    int sidx = idx[g];
    const float4* src = (const float4*)(x + (((size_t)b * SEQ + sidx) << 9));
    float4* dst = (float4*)(out + ((size_t)g << 9));
    dst[l]      = src[l];
    dst[l + 64] = src[l + 64];
    dst[l + 32] = src[l + 32];
    dst[l + 96] = src[l + 96];
}

extern "C" void kernel_launch(void* const* d_in, const int* in_sizes, int n_in,
                              void* d_out, int out_size, void* d_ws, size_t ws_size,
                              hipStream_t stream) {
    const float* x      = (const float*)d_in[0];
    const float* conv_w = (const float*)d_in[1];
    const float* conv_b = (const float*)d_in[2];
    const float* lin_w  = (const float*)d_in[3];
    const float* lin_b  = (const float*)d_in[4];
    const float* wbias  = (const float*)d_in[5];
    float* out = (float*)d_out;

    // Scratch inside d_out (268 MB f32): wT [0,16.8MB), y [16.8,33.6MB).
    // Both consumed by k_decode before k_gather overwrites d_out.
    // idx (512 KB) in d_ws.
    float* wT  = (float*)d_out;
    float* y   = (float*)((char*)d_out + (size_t)16777216);
    int*   idx = (int*)d_ws;

    hipLaunchKernelGGL(k_transpose_w, dim3(16384), dim3(256), 0, stream, conv_w, wT);
    hipLaunchKernelGGL(k_conv,        dim3(128, 8), dim3(256), 0, stream, x, wT, conv_b, y);
    hipLaunchKernelGGL(k_decode,      dim3(32),    dim3(256), 0, stream, y, lin_w, lin_b, wbias, idx);
    hipLaunchKernelGGL(k_gather,      dim3(16384), dim3(256), 0, stream, x, idx, out);
}

// Round 21
// 1016.924 us; speedup vs baseline: 1.0727x; 1.0727x over previous
//
#include <hip/hip_runtime.h>
#include <cmath>

#define BATCH 32
#define SEQ   2048
#define EMB   512
#define NOUT  256
#define PS    16
#define KW    16
#define JTOT  8192  // K*E flat contraction length, j = k*512 + i (i fastest)
#define KCL   288   // Eigen threaded gebp kc (linear dot: 512 = 288 + 224)
#define KS    32    // j-tile; 288 = 9*KS, tail 128 = 4*KS -> panel folds align

// sA swizzled word index (64-word rows): row kk + XOR word bits 2-4 by kk&7.
// Bijective per row, preserves 16B quads (only bits>=2 touched).
#define SWA(kk_, mw_) (((kk_) << 6) + ((mw_) ^ (((kk_) & 7) << 2)))

// async global->LDS, 16B per lane, wave-uniform LDS base + lane*16 dest
#define GLDS16(g_, l_) __builtin_amdgcn_global_load_lds(                      \
    (__attribute__((address_space(1))) const void*)(g_),                      \
    (__attribute__((address_space(3))) void*)(l_), 16, 0, 0)

// XLA EmitFastTanh / Eigen ptanh_float: rational approx, f32, FMA Horner.
__device__ __forceinline__ float xla_tanhf(float x) {
#pragma clang fp contract(off)
    float ax = fabsf(x);
    float xc = x;
    if (xc < -7.90531110763549805f) xc = -7.90531110763549805f;
    if (xc >  7.90531110763549805f) xc =  7.90531110763549805f;
    float x2 = xc * xc;
    float p = __builtin_fmaf(x2, -2.76076847742355e-16f, 2.00018790482477e-13f);
    p = __builtin_fmaf(x2, p, -8.60467152213735e-11f);
    p = __builtin_fmaf(x2, p,  5.12229709037114e-08f);
    p = __builtin_fmaf(x2, p,  1.48572235717979e-05f);
    p = __builtin_fmaf(x2, p,  6.37261928875436e-04f);
    p = __builtin_fmaf(x2, p,  4.89352455891786e-03f);
    float num = xc * p;
    float q = __builtin_fmaf(x2, 1.19825839466702e-06f, 1.18534705686654e-04f);
    q = __builtin_fmaf(x2, q, 2.26843463243900e-03f);
    q = __builtin_fmaf(x2, q, 4.89352518554385e-03f);
    float r = num / q;
    return (ax < 0.0004f) ? x : r;
}

// K1: wT[j][o] = conv_w[o][i][k],  j = k*512 + i  (XLA/Eigen im2col order)
__global__ __launch_bounds__(256) void k_transpose_w(const float* __restrict__ w,
                                                     float* __restrict__ wT) {
    int t = blockIdx.x * 256 + threadIdx.x;   // t = j*512 + o
    int o = t & 511;
    int i = (t >> 9) & 511;
    int k = t >> 18;
    wT[t] = w[(size_t)o * 8192 + i * 16 + k];
}

// K2: conv1d as LDS-tiled f32 GEMM, bit-exact Eigen gebp accumulation.
// Synthesis config: r18's tile (64m x 128o, traffic-proven) at r20's TLP:
// 512 thr (8 waves), 4x4 micro (16 acc), grid (128,4)=512 blocks = 2/CU
// = 16 waves/CU = 4 waves/SIMD. LDS 48 KB/block (2 blocks fit).
//  - sA XOR-swizzled (r18-measured: zero write conflicts, 2-way reads free)
//  - T14 order: LOAD_A (top, before B-DMAs) ... compute ... WRITE_A ... barrier
//  - sB: global_load_lds DMA, lane-linear, zero regs, zero conflicts.
// Per output: panels of kc=288 over j, sequential fmaf chain (pk), panels
// left-folded into ys at js%9==8 and js==255 -> identical bits to r9-r20.
__global__ __launch_bounds__(512, 4) void k_conv(const float* __restrict__ x,
                                                 const float* __restrict__ wT,
                                                 const float* __restrict__ cb,
                                                 float* __restrict__ y) {
#pragma clang fp contract(off)
    __shared__ __align__(16) float sA[2][KS * 64];    // 16 KB, swizzled [kk][m]
    __shared__ __align__(16) float sB[2][KS][128];    // 32 KB, linear (GLDS dest)

    int bn0 = blockIdx.x << 6;     // 0..127 -> 64-bn strip
    int b   = bn0 >> 8;
    int n0  = bn0 & 255;
    int o0  = blockIdx.y << 7;     // 0..3 -> 128-o strip

    int tid  = threadIdx.x;        // 0..511
    int tm   = tid & 15;           // 4 m-rows each (m = tm*4+mi)
    int tn   = tid >> 4;           // 4 o-cols each (o = tn*4+ni), 0..31
    int lane = tid & 63;
    int wv   = tid >> 6;           // wave id 0..7

    // A-staging role: thread = (kks 0..31, mg 0..15): col i0+kks, m-quad mg
    int kks = tid & 31;
    int mg  = tid >> 5;

    float ys[4][4], pk[4][4];
#pragma unroll
    for (int mi = 0; mi < 4; ++mi)
#pragma unroll
        for (int ni = 0; ni < 4; ++ni) { ys[mi][ni] = 0.0f; pk[mi][ni] = 0.0f; }

    const float* xb = x + (size_t)b * SEQ * EMB;

    float rs[4];   // A-stage regs (4 VGPR), only cross-compute liveness

    // A: 8 KB/js; thread loads 4 m-rows of its column (128B-coalesced/instr)
#define LOAD_A(js_)                                                            \
    {                                                                          \
        int k_ = (js_) >> 4;                                                   \
        const float* xcol = xb + ((((js_) & 15) << 5) + kks);                  \
        _Pragma("unroll")                                                      \
        for (int q = 0; q < 4; ++q) {                                          \
            int m = (mg << 2) + q;                                             \
            int s = ((n0 + m) << 3) - 4 + k_;                                  \
            rs[q] = (s >= 0 && s < SEQ) ? xcol[(size_t)s << 9] : 0.0f;         \
        }                                                                      \
    }

    // 1 b128 write per thread, XOR-swizzled (r18-proven pattern): conflict-free
#define WRITE_A(bf_)                                                           \
    {                                                                          \
        float4 v = make_float4(rs[0], rs[1], rs[2], rs[3]);                    \
        *(float4*)&sA[bf_][SWA(kks, (mg << 2))] = v;                           \
    }

    // B: 16 KB/js; 2 DMA insts per wave (8 waves), 2 kk-rows (512 B) per inst
#define STAGE_B(js_, bf_)                                                      \
    {                                                                          \
        _Pragma("unroll")                                                      \
        for (int t2 = 0; t2 < 2; ++t2) {                                       \
            int kkb = (wv << 2) + (t2 << 1);                                   \
            const float* gsrc = wT + (((size_t)((js_) << 5) + kkb + (lane >> 5)) << 9) \
                                   + o0 + ((lane & 31) << 2);                  \
            GLDS16(gsrc, &sB[bf_][kkb][0]);                                    \
        }                                                                      \
    }

    // prologue: stage js=0 into buffer 0
    LOAD_A(0);
    WRITE_A(0);
    STAGE_B(0, 0);
    __syncthreads();

    for (int js = 0; js < 256; ++js) {
        int cur = js & 1;
        if (js < 255) {
            LOAD_A(js + 1);                // A loads first (oldest in vm queue)
            STAGE_B(js + 1, cur ^ 1);      // B DMAs younger -> WRITE_A won't drain them
        }

        // micro-kernel: pk chains ascend in kk (exact Eigen panel order)
        // a-read: 2-way broadcast (free); b-read: 4 distinct addrs/wave,
        // 16-lane broadcast each -> conflict-free
#pragma unroll
        for (int kk = 0; kk < KS; ++kk) {
            float4 a  = *(const float4*)&sA[cur][SWA(kk, tm << 2)];
            float4 bq = *(const float4*)&sB[cur][kk][tn << 2];
            float av[4] = {a.x, a.y, a.z, a.w};
            float bv[4] = {bq.x, bq.y, bq.z, bq.w};
#pragma unroll
            for (int mi = 0; mi < 4; ++mi)
#pragma unroll
                for (int ni = 0; ni < 4; ++ni)
                    pk[mi][ni] = __builtin_fmaf(av[mi], bv[ni], pk[mi][ni]);
        }
        // panel left-fold (ys += pk) at kc=288 boundaries and the 128 tail
        if ((js % 9) == 8 || js == 255) {
#pragma unroll
            for (int mi = 0; mi < 4; ++mi)
#pragma unroll
                for (int ni = 0; ni < 4; ++ni) {
                    ys[mi][ni] = ys[mi][ni] + pk[mi][ni];
                    pk[mi][ni] = 0.0f;
                }
        }
        // write A for js+1 (waits only the A loads; B DMAs stay in flight)
        if (js < 255) WRITE_A(cur ^ 1);
        __syncthreads();   // drains vmcnt(0) (B landed during compute), barrier
    }

    // epilogue: bias add (exact r9 order) + store
    const float* cbp = cb + o0 + (tn << 2);
#pragma unroll
    for (int mi = 0; mi < 4; ++mi) {
        int n = n0 + (tm << 2) + mi;
        float* dst = y + (((size_t)(b << 8) + n) << 9) + o0 + (tn << 2);
#pragma unroll
        for (int ni = 0; ni < 4; ++ni)
            dst[ni] = ys[mi][ni] + cbp[ni];
    }
#undef LOAD_A
#undef WRITE_A
#undef STAGE_B
}

// K3: per (b,n): off = relu(y) @ lin_w.T + lin_b with Eigen kc=288 panel split
// (512 = 288 + 224), then decode op-for-op in f32 (contract off), XLA tanh,
// jax-f32 linspace t (t = p * f32(1/15)).
__global__ __launch_bounds__(256) void k_decode(const float* __restrict__ y,
                                               const float* __restrict__ lw,
                                               const float* __restrict__ lb,
                                               const float* __restrict__ wb,
                                               int* __restrict__ idx) {
#pragma clang fp contract(off)
    int bn = blockIdx.x * 256 + threadIdx.x;   // 0..8191
    if (bn >= BATCH * NOUT) return;
    const float* yy = y + ((size_t)bn << 9);

    float s0, s1;
    {
        float p0 = 0.0f, p1 = 0.0f;
        for (int e = 0; e < KCL; ++e) {
            float v = yy[e];
            float r = v > 0.0f ? v : 0.0f;
            p0 = __builtin_fmaf(r, lw[e],       p0);
            p1 = __builtin_fmaf(r, lw[EMB + e], p1);
        }
        s0 = p0; s1 = p1;                  // panel 0 stores (beta=0)
    }
    {
        float p0 = 0.0f, p1 = 0.0f;
        for (int e = KCL; e < EMB; ++e) {
            float v = yy[e];
            float r = v > 0.0f ? v : 0.0f;
            p0 = __builtin_fmaf(r, lw[e],       p0);
            p1 = __builtin_fmaf(r, lw[EMB + e], p1);
        }
        s0 = s0 + p0; s1 = s1 + p1;        // panel 1 accumulates
    }
    float off0 = s0 + lb[0];
    float off1 = s1 + lb[1];

    int n = bn & (NOUT - 1);
    float anchor = (0.5f + (float)n) / 256.0f;        // exact in f32
    float dx  = xla_tanhf(off0) * 0.00390625f;        // * poi (2^-8, exact)
    float a1  = off1 + wb[0];
    float tww = xla_tanhf(a1);
    float rwv = tww > 0.0f ? tww : 0.0f;
    float dwv = rwv * 0.00390625f;
    float adx = anchor + dx;                          // left-assoc like jnp
    float x0 = adx - dwv; x0 = x0 < 0.0f ? 0.0f : (x0 > 1.0f ? 1.0f : x0);
    float x1 = adx + dwv; x1 = x1 < 0.0f ? 0.0f : (x1 > 1.0f ? 1.0f : x1);

    const float delta = 1.0f / 15.0f;                 // f32 0.06666667
#pragma unroll
    for (int p = 0; p < PS; ++p) {
        float t  = (float)p * delta;                  // jax linspace: iota*delta, f32
        float om = 1.0f - t;
        float gs = x0 * om + x1 * t;                  // mul,mul,add — contract off
        float gxn = 2.0f * gs - 1.0f;
        float gp1 = gxn + 1.0f;
        float ixx = (gp1 * 2048.0f - 1.0f) * 0.5f;
        float rr = rintf(ixx);                        // round half-even
        int id = (int)rr;
        id = id < 0 ? 0 : (id > SEQ - 1 ? SEQ - 1 : id);
        idx[bn * PS + p] = id;
    }
}

// K4: out[g][:] = x[b][idx[g]][:] (exact f32 row copy, 2048 B/row).
// Coarsened: 8 rows per block, 256 thr.
__global__ __launch_bounds__(256) void k_gather(const float* __restrict__ x,
                                                const int* __restrict__ idx,
                                                float* __restrict__ out) {
    int g0 = blockIdx.x << 3;           // first of 8 rows, 16384 blocks
    int r  = threadIdx.x >> 5;          // row 0..7
    int l  = threadIdx.x & 31;          // lane-in-row 0..31
    int g  = g0 + r;
    int b  = g >> 12;
    int sidx = idx[g];
    const float4* src = (const float4*)(x + (((size_t)b * SEQ + sidx) << 9));
    float4* dst = (float4*)(out + ((size_t)g << 9));
    dst[l]      = src[l];
    dst[l + 64] = src[l + 64];
    dst[l + 32] = src[l + 32];
    dst[l + 96] = src[l + 96];
}

extern "C" void kernel_launch(void* const* d_in, const int* in_sizes, int n_in,
                              void* d_out, int out_size, void* d_ws, size_t ws_size,
                              hipStream_t stream) {
    const float* x      = (const float*)d_in[0];
    const float* conv_w = (const float*)d_in[1];
    const float* conv_b = (const float*)d_in[2];
    const float* lin_w  = (const float*)d_in[3];
    const float* lin_b  = (const float*)d_in[4];
    const float* wbias  = (const float*)d_in[5];
    float* out = (float*)d_out;

    // Scratch inside d_out (268 MB f32): wT [0,16.8MB), y [16.8,33.6MB).
    // Both consumed by k_decode before k_gather overwrites d_out.
    // idx (512 KB) in d_ws.
    float* wT  = (float*)d_out;
    float* y   = (float*)((char*)d_out + (size_t)16777216);
    int*   idx = (int*)d_ws;

    hipLaunchKernelGGL(k_transpose_w, dim3(16384), dim3(256), 0, stream, conv_w, wT);
    hipLaunchKernelGGL(k_conv,        dim3(128, 4), dim3(512), 0, stream, x, wT, conv_b, y);
    hipLaunchKernelGGL(k_decode,      dim3(32),    dim3(256), 0, stream, y, lin_w, lin_b, wbias, idx);
    hipLaunchKernelGGL(k_gather,      dim3(16384), dim3(256), 0, stream, x, idx, out);
}

// Round 22
// 994.065 us; speedup vs baseline: 1.0974x; 1.0230x over previous
//
#include <hip/hip_runtime.h>
#include <cmath>

#define BATCH 32
#define SEQ   2048
#define EMB   512
#define NOUT  256
#define PS    16
#define KW    16
#define JTOT  8192  // K*E flat contraction length, j = k*512 + i (i fastest)
#define KCL   288   // Eigen threaded gebp kc (linear dot: 512 = 288 + 224)
#define KS    32    // j-tile; 288 = 9*KS, tail 128 = 4*KS -> panel folds align

// sA swizzled word index (64-word rows): row kk + XOR word bits 2-4 by kk&7.
// Bijective per row, preserves 16B quads (only bits>=2 touched).
#define SWA(kk_, mw_) (((kk_) << 6) + ((mw_) ^ (((kk_) & 7) << 2)))

// async global->LDS, 16B per lane, wave-uniform LDS base + lane*16 dest
#define GLDS16(g_, l_) __builtin_amdgcn_global_load_lds(                      \
    (__attribute__((address_space(1))) const void*)(g_),                      \
    (__attribute__((address_space(3))) void*)(l_), 16, 0, 0)

// XLA EmitFastTanh / Eigen ptanh_float: rational approx, f32, FMA Horner.
__device__ __forceinline__ float xla_tanhf(float x) {
#pragma clang fp contract(off)
    float ax = fabsf(x);
    float xc = x;
    if (xc < -7.90531110763549805f) xc = -7.90531110763549805f;
    if (xc >  7.90531110763549805f) xc =  7.90531110763549805f;
    float x2 = xc * xc;
    float p = __builtin_fmaf(x2, -2.76076847742355e-16f, 2.00018790482477e-13f);
    p = __builtin_fmaf(x2, p, -8.60467152213735e-11f);
    p = __builtin_fmaf(x2, p,  5.12229709037114e-08f);
    p = __builtin_fmaf(x2, p,  1.48572235717979e-05f);
    p = __builtin_fmaf(x2, p,  6.37261928875436e-04f);
    p = __builtin_fmaf(x2, p,  4.89352455891786e-03f);
    float num = xc * p;
    float q = __builtin_fmaf(x2, 1.19825839466702e-06f, 1.18534705686654e-04f);
    q = __builtin_fmaf(x2, q, 2.26843463243900e-03f);
    q = __builtin_fmaf(x2, q, 4.89352518554385e-03f);
    float r = num / q;
    return (ax < 0.0004f) ? x : r;
}

// K1: wT[j][o] = conv_w[o][i][k],  j = k*512 + i  (XLA/Eigen im2col order)
__global__ __launch_bounds__(256) void k_transpose_w(const float* __restrict__ w,
                                                     float* __restrict__ wT) {
    int t = blockIdx.x * 256 + threadIdx.x;   // t = j*512 + o
    int o = t & 511;
    int i = (t >> 9) & 511;
    int k = t >> 18;
    wT[t] = w[(size_t)o * 8192 + i * 16 + k];
}

// K2: conv1d as LDS-tiled f32 GEMM, bit-exact Eigen gebp accumulation.
// Measured-best config (r18/r19): 64m x 128o tile, 4x8 micro, 256 thr,
// grid (128,4)=512 blocks = 2 blocks/CU = 2 waves/SIMD.
//  - sA XOR-swizzled: A-writes conflict-free, A-reads 2-way/free
//  - T14 order: LOAD_A (top, before B-DMAs) ... compute ... WRITE_A ... barrier
//  - sB: global_load_lds DMA, lane-linear, zero regs, zero conflicts.
// Per output: panels of kc=288 over j, sequential fmaf chain (pk), panels
// left-folded into ys at js%9==8 and js==255 -> identical bits to r9-r21.
__global__ __launch_bounds__(256, 2) void k_conv(const float* __restrict__ x,
                                                 const float* __restrict__ wT,
                                                 const float* __restrict__ cb,
                                                 float* __restrict__ y) {
#pragma clang fp contract(off)
    __shared__ __align__(16) float sA[2][KS * 64];    // 16 KB, swizzled [kk][m]
    __shared__ __align__(16) float sB[2][KS][128];    // 32 KB, linear (GLDS dest)

    int bn0 = blockIdx.x << 6;     // 0..127 -> 64-bn strip
    int b   = bn0 >> 8;
    int n0  = bn0 & 255;
    int o0  = blockIdx.y << 7;     // 0..3 -> 128-o strip

    int tid  = threadIdx.x;
    int tm   = tid & 15;           // 4 m-rows each (m = tm*4+mi)
    int tn   = tid >> 4;           // 8 o-cols each (o = tn*8+ni)
    int lane = tid & 63;
    int wv   = tid >> 6;           // wave id 0..3

    // A-staging role: thread = (kks 0..31, mg 0..7): col i0+kks, m-octet mg
    int kks = tid & 31;
    int mg  = tid >> 5;

    float ys[4][8], pk[4][8];
#pragma unroll
    for (int mi = 0; mi < 4; ++mi)
#pragma unroll
        for (int ni = 0; ni < 8; ++ni) { ys[mi][ni] = 0.0f; pk[mi][ni] = 0.0f; }

    const float* xb = x + (size_t)b * SEQ * EMB;

    float rs[8];   // A-stage regs (8 VGPR), only cross-compute liveness

    // A: 8 KB/js; thread loads 8 m-rows of its column (128B-coalesced/instr)
#define LOAD_A(js_)                                                            \
    {                                                                          \
        int k_ = (js_) >> 4;                                                   \
        const float* xcol = xb + ((((js_) & 15) << 5) + kks);                  \
        _Pragma("unroll")                                                      \
        for (int q = 0; q < 8; ++q) {                                          \
            int m = (mg << 3) + q;                                             \
            int s = ((n0 + m) << 3) - 4 + k_;                                  \
            rs[q] = (s >= 0 && s < SEQ) ? xcol[(size_t)s << 9] : 0.0f;         \
        }                                                                      \
    }

    // 2 b128 writes, XOR-swizzled: 8 words/bank per instr (conflict-free)
#define WRITE_A(bf_)                                                           \
    {                                                                          \
        _Pragma("unroll")                                                      \
        for (int wq = 0; wq < 2; ++wq) {                                       \
            float4 v = make_float4(rs[wq * 4], rs[wq * 4 + 1],                 \
                                   rs[wq * 4 + 2], rs[wq * 4 + 3]);            \
            *(float4*)&sA[bf_][SWA(kks, (mg << 3) + (wq << 2))] = v;           \
        }                                                                      \
    }

    // B: 16 KB/js; 4 DMA insts per wave, 2 kk-rows (512 B each) per inst
#define STAGE_B(js_, bf_)                                                      \
    {                                                                          \
        _Pragma("unroll")                                                      \
        for (int t2 = 0; t2 < 4; ++t2) {                                       \
            int kkb = (wv << 3) + (t2 << 1);                                   \
            const float* gsrc = wT + (((size_t)((js_) << 5) + kkb + (lane >> 5)) << 9) \
                                   + o0 + ((lane & 31) << 2);                  \
            GLDS16(gsrc, &sB[bf_][kkb][0]);                                    \
        }                                                                      \
    }

    // prologue: stage js=0 into buffer 0
    LOAD_A(0);
    WRITE_A(0);
    STAGE_B(0, 0);
    __syncthreads();

    for (int js = 0; js < 256; ++js) {
        int cur = js & 1;
        if (js < 255) {
            LOAD_A(js + 1);                // A loads first (oldest in vm queue)
            STAGE_B(js + 1, cur ^ 1);      // B DMAs younger -> WRITE_A won't drain them
        }

        // micro-kernel: pk chains ascend in kk (exact Eigen panel order)
#pragma unroll
        for (int kk = 0; kk < KS; ++kk) {
            float4 a  = *(const float4*)&sA[cur][SWA(kk, tm << 2)];
            float4 b0 = *(const float4*)&sB[cur][kk][tn << 3];
            float4 b1 = *(const float4*)&sB[cur][kk][(tn << 3) + 4];
            float av[4] = {a.x, a.y, a.z, a.w};
            float bv[8] = {b0.x, b0.y, b0.z, b0.w, b1.x, b1.y, b1.z, b1.w};
#pragma unroll
            for (int mi = 0; mi < 4; ++mi)
#pragma unroll
                for (int ni = 0; ni < 8; ++ni)
                    pk[mi][ni] = __builtin_fmaf(av[mi], bv[ni], pk[mi][ni]);
        }
        // panel left-fold (ys += pk) at kc=288 boundaries and the 128 tail
        if ((js % 9) == 8 || js == 255) {
#pragma unroll
            for (int mi = 0; mi < 4; ++mi)
#pragma unroll
                for (int ni = 0; ni < 8; ++ni) {
                    ys[mi][ni] = ys[mi][ni] + pk[mi][ni];
                    pk[mi][ni] = 0.0f;
                }
        }
        // write A for js+1 (waits vmcnt(4): A landed, B still in flight)
        if (js < 255) WRITE_A(cur ^ 1);
        __syncthreads();   // drains vmcnt(0) (B landed during compute), barrier
    }

    // epilogue: bias add (exact r9 order) + store (verified mapping)
    const float* cbp = cb + o0 + (tn << 3);
#pragma unroll
    for (int mi = 0; mi < 4; ++mi) {
        int n = n0 + (tm << 2) + mi;
        float* dst = y + (((size_t)(b << 8) + n) << 9) + o0 + (tn << 3);
#pragma unroll
        for (int ni = 0; ni < 8; ++ni)
            dst[ni] = ys[mi][ni] + cbp[ni];
    }
#undef LOAD_A
#undef WRITE_A
#undef STAGE_B
}

// K3: per (b,n): off = relu(y) @ lin_w.T + lin_b with Eigen kc=288 panel split
// (512 = 288 + 224), then decode op-for-op in f32 (contract off), XLA tanh,
// jax-f32 linspace t (t = p * f32(1/15)).
__global__ __launch_bounds__(256) void k_decode(const float* __restrict__ y,
                                               const float* __restrict__ lw,
                                               const float* __restrict__ lb,
                                               const float* __restrict__ wb,
                                               int* __restrict__ idx) {
#pragma clang fp contract(off)
    int bn = blockIdx.x * 256 + threadIdx.x;   // 0..8191
    if (bn >= BATCH * NOUT) return;
    const float* yy = y + ((size_t)bn << 9);

    float s0, s1;
    {
        float p0 = 0.0f, p1 = 0.0f;
        for (int e = 0; e < KCL; ++e) {
            float v = yy[e];
            float r = v > 0.0f ? v : 0.0f;
            p0 = __builtin_fmaf(r, lw[e],       p0);
            p1 = __builtin_fmaf(r, lw[EMB + e], p1);
        }
        s0 = p0; s1 = p1;                  // panel 0 stores (beta=0)
    }
    {
        float p0 = 0.0f, p1 = 0.0f;
        for (int e = KCL; e < EMB; ++e) {
            float v = yy[e];
            float r = v > 0.0f ? v : 0.0f;
            p0 = __builtin_fmaf(r, lw[e],       p0);
            p1 = __builtin_fmaf(r, lw[EMB + e], p1);
        }
        s0 = s0 + p0; s1 = s1 + p1;        // panel 1 accumulates
    }
    float off0 = s0 + lb[0];
    float off1 = s1 + lb[1];

    int n = bn & (NOUT - 1);
    float anchor = (0.5f + (float)n) / 256.0f;        // exact in f32
    float dx  = xla_tanhf(off0) * 0.00390625f;        // * poi (2^-8, exact)
    float a1  = off1 + wb[0];
    float tww = xla_tanhf(a1);
    float rwv = tww > 0.0f ? tww : 0.0f;
    float dwv = rwv * 0.00390625f;
    float adx = anchor + dx;                          // left-assoc like jnp
    float x0 = adx - dwv; x0 = x0 < 0.0f ? 0.0f : (x0 > 1.0f ? 1.0f : x0);
    float x1 = adx + dwv; x1 = x1 < 0.0f ? 0.0f : (x1 > 1.0f ? 1.0f : x1);

    const float delta = 1.0f / 15.0f;                 // f32 0.06666667
#pragma unroll
    for (int p = 0; p < PS; ++p) {
        float t  = (float)p * delta;                  // jax linspace: iota*delta, f32
        float om = 1.0f - t;
        float gs = x0 * om + x1 * t;                  // mul,mul,add — contract off
        float gxn = 2.0f * gs - 1.0f;
        float gp1 = gxn + 1.0f;
        float ixx = (gp1 * 2048.0f - 1.0f) * 0.5f;
        float rr = rintf(ixx);                        // round half-even
        int id = (int)rr;
        id = id < 0 ? 0 : (id > SEQ - 1 ? SEQ - 1 : id);
        idx[bn * PS + p] = id;
    }
}

// K4: out[g][:] = x[b][idx[g]][:] (exact f32 row copy, 2048 B/row).
// Coarsened: 8 rows per block, 256 thr.
__global__ __launch_bounds__(256) void k_gather(const float* __restrict__ x,
                                                const int* __restrict__ idx,
                                                float* __restrict__ out) {
    int g0 = blockIdx.x << 3;           // first of 8 rows, 16384 blocks
    int r  = threadIdx.x >> 5;          // row 0..7
    int l  = threadIdx.x & 31;          // lane-in-row 0..31
    int g  = g0 + r;
    int b  = g >> 12;
    int sidx = idx[g];
    const float4* src = (const float4*)(x + (((size_t)b * SEQ + sidx) << 9));
    float4* dst = (float4*)(out + ((size_t)g << 9));
    dst[l]      = src[l];
    dst[l + 64] = src[l + 64];
    dst[l + 32] = src[l + 32];
    dst[l + 96] = src[l + 96];
}

extern "C" void kernel_launch(void* const* d_in, const int* in_sizes, int n_in,
                              void* d_out, int out_size, void* d_ws, size_t ws_size,
                              hipStream_t stream) {
    const float* x      = (const float*)d_in[0];
    const float* conv_w = (const float*)d_in[1];
    const float* conv_b = (const float*)d_in[2];
    const float* lin_w  = (const float*)d_in[3];
    const float* lin_b  = (const float*)d_in[4];
    const float* wbias  = (const float*)d_in[5];
    float* out = (float*)d_out;

    // Scratch inside d_out (268 MB f32): wT [0,16.8MB), y [16.8,33.6MB).
    // Both consumed by k_decode before k_gather overwrites d_out.
    // idx (512 KB) in d_ws.
    float* wT  = (float*)d_out;
    float* y   = (float*)((char*)d_out + (size_t)16777216);
    int*   idx = (int*)d_ws;

    hipLaunchKernelGGL(k_transpose_w, dim3(16384), dim3(256), 0, stream, conv_w, wT);
    hipLaunchKernelGGL(k_conv,        dim3(128, 4), dim3(256), 0, stream, x, wT, conv_b, y);
    hipLaunchKernelGGL(k_decode,      dim3(32),    dim3(256), 0, stream, y, lin_w, lin_b, wbias, idx);
    hipLaunchKernelGGL(k_gather,      dim3(16384), dim3(256), 0, stream, x, idx, out);
}